// Round 4
// baseline (926.784 us; speedup 1.0000x reference)
//
#include <hip/hip_runtime.h>
#include <hip/hip_bf16.h>

#define N_NODES 50000
#define N_EDGES 800000
#define F_IN 128
#define HEADS 8
#define HID 16
#define HC 128   // HEADS*HID
#define NB 16    // nodes per block in fused kernel

__device__ __forceinline__ float bf2f(unsigned short u) {
  union { unsigned int i; float f; } v;
  v.i = (unsigned int)u << 16;
  return v.f;
}

// ---------------------------------------------------------------------------
// K1: fused dual GEMM  xl = x@Wl + bl, xr = x@Wr + br  -> stored as bf16
// ---------------------------------------------------------------------------
__global__ __launch_bounds__(256) void k_gemm(
    const float* __restrict__ x,
    const float* __restrict__ Wl, const float* __restrict__ bl,
    const float* __restrict__ Wr, const float* __restrict__ br,
    __hip_bfloat16* __restrict__ xl, __hip_bfloat16* __restrict__ xr) {
  __shared__ float xs[16 * 128];
  const int t = threadIdx.x;
  const int block_row = blockIdx.x * 16;

  const float4* xsrc = (const float4*)(x + (size_t)block_row * F_IN);
  float4* xd = (float4*)xs;
  xd[t] = xsrc[t];
  xd[t + 256] = xsrc[t + 256];
  __syncthreads();

  const int col = t & 127;
  const bool right = t >= 128;
  const float* __restrict__ W = right ? Wr : Wl;
  const float* __restrict__ bv = right ? br : bl;

  float acc[16];
#pragma unroll
  for (int r = 0; r < 16; ++r) acc[r] = 0.f;

  for (int k = 0; k < 128; k += 4) {
    const float w0 = W[(k + 0) * HC + col];
    const float w1 = W[(k + 1) * HC + col];
    const float w2 = W[(k + 2) * HC + col];
    const float w3 = W[(k + 3) * HC + col];
#pragma unroll
    for (int r = 0; r < 16; ++r) {
      const float4 xv = *((const float4*)(xs + r * 128 + k));  // wave-uniform LDS broadcast
      acc[r] = fmaf(xv.x, w0, acc[r]);
      acc[r] = fmaf(xv.y, w1, acc[r]);
      acc[r] = fmaf(xv.z, w2, acc[r]);
      acc[r] = fmaf(xv.w, w3, acc[r]);
    }
  }
  const float b = bv[col];
  __hip_bfloat16* __restrict__ dst = right ? xr : xl;
#pragma unroll
  for (int r = 0; r < 16; ++r)
    dst[(size_t)(block_row + r) * HC + col] = __float2bfloat16(acc[r] + b);
}

// ---------------------------------------------------------------------------
// K2a: degree histogram over dst
// ---------------------------------------------------------------------------
__global__ __launch_bounds__(256) void k_deg(const int* __restrict__ eidx,
                                             int* __restrict__ deg) {
  const int e = blockIdx.x * 256 + threadIdx.x;
  if (e < N_EDGES) atomicAdd(&deg[eidx[N_EDGES + e]], 1);
}

// ---------------------------------------------------------------------------
// K2b: single-block scan of degrees -> offs[0..N_NODES]
// ---------------------------------------------------------------------------
__global__ __launch_bounds__(1024) void k_scan(const int* __restrict__ deg,
                                               int* __restrict__ offs) {
  __shared__ int sm[1024];
  const int t = threadIdx.x;
  const int per = (N_NODES + 1023) / 1024;  // 49
  const int base = t * per;
  int s = 0;
  for (int i = 0; i < per; ++i) {
    const int idx = base + i;
    if (idx < N_NODES) s += deg[idx];
  }
  sm[t] = s;
  __syncthreads();
  for (int off = 1; off < 1024; off <<= 1) {
    const int add = (t >= off) ? sm[t - off] : 0;
    __syncthreads();
    sm[t] += add;
    __syncthreads();
  }
  int excl = sm[t] - s;
  for (int i = 0; i < per; ++i) {
    const int idx = base + i;
    if (idx < N_NODES) {
      offs[idx] = excl;
      excl += deg[idx];
    }
  }
  if (t == 1023) offs[N_NODES] = sm[1023];
}

// ---------------------------------------------------------------------------
// K2c: scatter packed edge records {src, dst, ea.x, ea.y} into CSR order
// ---------------------------------------------------------------------------
__global__ __launch_bounds__(256) void k_scatter(
    const int* __restrict__ eidx, const float* __restrict__ eattr,
    const int* __restrict__ offs, int* __restrict__ cursor,
    int4* __restrict__ epack) {
  const int e = blockIdx.x * 256 + threadIdx.x;
  if (e < N_EDGES) {
    const int src = eidx[e];
    const int d = eidx[N_EDGES + e];
    const float2 ea = *(const float2*)(eattr + (size_t)e * 2);
    const int pos = atomicAdd(&cursor[d], 1);
    epack[offs[d] + pos] =
        make_int4(src, d, __float_as_int(ea.x), __float_as_int(ea.y));
  }
}

// ---------------------------------------------------------------------------
// K3: fused edge-parallel attention + aggregation + BN partial stats.
// Block owns NB=16 consecutive nodes (contiguous CSR edge range). Threads
// iterate (slot, head) pairs: compute logit -> ex, accumulate ex*xl into
// LDS accumulators (atomic), denom likewise. Epilogue normalizes, writes out,
// and reduces per-channel sum/sumsq into global stats.
// ---------------------------------------------------------------------------
__global__ __launch_bounds__(256) void k_fused2(
    const int* __restrict__ offs, const int4* __restrict__ epack,
    const __hip_bfloat16* __restrict__ xl, const __hip_bfloat16* __restrict__ xr,
    const float* __restrict__ We, const float* __restrict__ be,
    const float* __restrict__ att,
    float* __restrict__ outp, float* __restrict__ stats) {
  __shared__ float accs[NB * 128];
  __shared__ float dns[NB * 8];
  __shared__ unsigned int xrs[NB * 64];  // NB rows x 128 bf16
  __shared__ float red[256];
  const int tid = threadIdx.x;
  const int n0 = blockIdx.x * NB;

  // stage xr rows (NB*128*2B = 4KB -> 256 uint4, 1 per thread)
  ((uint4*)xrs)[tid] = ((const uint4*)(xr + (size_t)n0 * HC))[tid];
  // zero accumulators
#pragma unroll
  for (int k = 0; k < NB * 128 / 256; ++k) accs[tid + k * 256] = 0.f;
  if (tid < NB * 8) dns[tid] = 0.f;
  const int e_beg = offs[n0];
  const int e_end = offs[n0 + NB];
  __syncthreads();

  const int EH = (e_end - e_beg) * 8;
  for (int idx = tid; idx < EH; idx += 256) {
    const int slot = e_beg + (idx >> 3);
    const int h = idx & 7;
    const int4 rec = epack[slot];
    const int src = rec.x;
    const int nrel = rec.y - n0;
    const float eax = __int_as_float(rec.z);
    const float eay = __int_as_float(rec.w);

    union { uint4 v[2]; unsigned int u[8]; } A;
    const uint4* xl4 = (const uint4*)(xl + (size_t)src * HC + h * HID);
    A.v[0] = xl4[0];
    A.v[1] = xl4[1];
    const unsigned int* xru = &xrs[nrel * 64 + h * 8];

    float xv[16];
    float logit = 0.f;
#pragma unroll
    for (int jj = 0; jj < 4; ++jj) {
      const int c = h * HID + jj * 4;
      const float4 w0 = *(const float4*)(We + c);
      const float4 w1 = *(const float4*)(We + HC + c);
      const float4 bb = *(const float4*)(be + c);
      const float4 av = *(const float4*)(att + c);
      const unsigned int ua0 = A.u[jj * 2], ua1 = A.u[jj * 2 + 1];
      const unsigned int ub0 = xru[jj * 2], ub1 = xru[jj * 2 + 1];
      const float x0 = bf2f((unsigned short)ua0);
      const float x1 = bf2f((unsigned short)(ua0 >> 16));
      const float x2 = bf2f((unsigned short)ua1);
      const float x3 = bf2f((unsigned short)(ua1 >> 16));
      xv[jj * 4 + 0] = x0;
      xv[jj * 4 + 1] = x1;
      xv[jj * 4 + 2] = x2;
      xv[jj * 4 + 3] = x3;
      float m0 = x0 + bf2f((unsigned short)ub0) +
                 fmaf(eax, w0.x, fmaf(eay, w1.x, bb.x));
      float m1 = x1 + bf2f((unsigned short)(ub0 >> 16)) +
                 fmaf(eax, w0.y, fmaf(eay, w1.y, bb.y));
      float m2 = x2 + bf2f((unsigned short)ub1) +
                 fmaf(eax, w0.z, fmaf(eay, w1.z, bb.z));
      float m3 = x3 + bf2f((unsigned short)(ub1 >> 16)) +
                 fmaf(eax, w0.w, fmaf(eay, w1.w, bb.w));
      m0 = m0 > 0.f ? m0 : 0.2f * m0;
      m1 = m1 > 0.f ? m1 : 0.2f * m1;
      m2 = m2 > 0.f ? m2 : 0.2f * m2;
      m3 = m3 > 0.f ? m3 : 0.2f * m3;
      logit = fmaf(m0, av.x, logit);
      logit = fmaf(m1, av.y, logit);
      logit = fmaf(m2, av.z, logit);
      logit = fmaf(m3, av.w, logit);
    }
    const float exv = __expf(logit);
    atomicAdd(&dns[nrel * 8 + h], exv);
    float* ap = &accs[nrel * 128 + h * HID];
#pragma unroll
    for (int j = 0; j < 16; ++j) atomicAdd(&ap[j], exv * xv[j]);
  }
  __syncthreads();

  // epilogue: normalize, write out, per-channel stats partials
  float s1 = 0.f, s2 = 0.f;
#pragma unroll
  for (int k = 0; k < NB * 128 / 256; ++k) {
    const int i = tid + k * 256;
    const int nrel = i >> 7;
    const int c = i & 127;  // == tid & 127 for all k (stride 256)
    const float dn = dns[nrel * 8 + (c >> 4)];
    const float inv = dn > 0.f ? 1.0f / dn : 0.f;
    const float v = accs[i] * inv;
    outp[(size_t)(n0 + nrel) * HC + c] = v;
    s1 += v;
    s2 = fmaf(v, v, s2);
  }
  red[tid] = s1;
  __syncthreads();
  if (tid < 128) atomicAdd(&stats[tid], red[tid] + red[tid + 128]);
  __syncthreads();
  red[tid] = s2;
  __syncthreads();
  if (tid < 128) atomicAdd(&stats[128 + tid], red[tid] + red[tid + 128]);
}

// ---------------------------------------------------------------------------
// K4: BatchNorm (batch stats) + LeakyReLU(0.01), in place on outp
// ---------------------------------------------------------------------------
__global__ __launch_bounds__(256) void k_bn(const float* __restrict__ stats,
                                            const float* __restrict__ gamma,
                                            const float* __restrict__ beta,
                                            float* __restrict__ outp) {
  const int i = blockIdx.x * 256 + threadIdx.x;
  if (i >= N_NODES * HC) return;
  const int c = i & 127;
  const float mean = stats[c] * (1.0f / N_NODES);
  const float var = stats[128 + c] * (1.0f / N_NODES) - mean * mean;
  const float rstd = rsqrtf(var + 1e-5f);
  float v = (outp[i] - mean) * rstd * gamma[c] + beta[c];
  outp[i] = v > 0.f ? v : 0.01f * v;
}

// ---------------------------------------------------------------------------
extern "C" void kernel_launch(void* const* d_in, const int* in_sizes, int n_in,
                              void* d_out, int out_size, void* d_ws, size_t ws_size,
                              hipStream_t stream) {
  const float* x     = (const float*)d_in[0];
  const int*   eidx  = (const int*)d_in[1];
  const float* eattr = (const float*)d_in[2];
  const float* Wl    = (const float*)d_in[3];
  const float* bl    = (const float*)d_in[4];
  const float* Wr    = (const float*)d_in[5];
  const float* br    = (const float*)d_in[6];
  const float* We    = (const float*)d_in[7];
  const float* be    = (const float*)d_in[8];
  const float* att   = (const float*)d_in[9];
  // d_in[10] = bias: cancels exactly in BatchNorm mean subtraction -> unused
  const float* gamma = (const float*)d_in[11];
  const float* beta  = (const float*)d_in[12];
  float* out = (float*)d_out;

  char* ws = (char*)d_ws;
  size_t off = 0;
  auto alloc = [&](size_t bytes) {
    size_t o = off;
    off = (off + bytes + 15) & ~size_t(15);
    return o;
  };
  // zero-initialized region first
  const size_t o_deg   = alloc((size_t)(N_NODES + 1) * 4);
  const size_t o_cur   = alloc((size_t)N_NODES * 4);
  const size_t o_stats = alloc(256 * 4);
  const size_t zero_bytes = off;
  // non-zeroed scratch
  const size_t o_offs = alloc((size_t)(N_NODES + 1) * 4);
  const size_t o_ep   = alloc((size_t)N_EDGES * 16);
  const size_t o_xl   = alloc((size_t)N_NODES * HC * 2);
  const size_t o_xr   = alloc((size_t)N_NODES * HC * 2);
  (void)ws_size; (void)in_sizes; (void)n_in; (void)out_size;

  int*   deg   = (int*)(ws + o_deg);
  int*   cur   = (int*)(ws + o_cur);
  float* stats = (float*)(ws + o_stats);
  int*   offs  = (int*)(ws + o_offs);
  int4*  epack = (int4*)(ws + o_ep);
  __hip_bfloat16* xl = (__hip_bfloat16*)(ws + o_xl);
  __hip_bfloat16* xr = (__hip_bfloat16*)(ws + o_xr);

  hipMemsetAsync(ws, 0, zero_bytes, stream);

  k_gemm<<<N_NODES / 16, 256, 0, stream>>>(x, Wl, bl, Wr, br, xl, xr);
  k_deg<<<(N_EDGES + 255) / 256, 256, 0, stream>>>(eidx, deg);
  k_scan<<<1, 1024, 0, stream>>>(deg, offs);
  k_scatter<<<(N_EDGES + 255) / 256, 256, 0, stream>>>(eidx, eattr, offs, cur, epack);
  k_fused2<<<N_NODES / NB, 256, 0, stream>>>(offs, epack, xl, xr, We, be, att,
                                             out, stats);
  k_bn<<<(N_NODES * HC + 255) / 256, 256, 0, stream>>>(stats, gamma, beta, out);
}

// Round 5
// 436.716 us; speedup vs baseline: 2.1222x; 2.1222x over previous
//
#include <hip/hip_runtime.h>
#include <hip/hip_bf16.h>

#define N_NODES 50000
#define N_EDGES 800000
#define HEADS 8
#define HID 16
#define HC 128  // HEADS*HID

typedef __attribute__((ext_vector_type(8))) short bf16x8;
typedef __attribute__((ext_vector_type(4))) float f32x4;

__device__ __forceinline__ float bf2f(unsigned short u) {
  union { unsigned int i; float f; } v;
  v.i = (unsigned int)u << 16;
  return v.f;
}
__device__ __forceinline__ unsigned short f2bf(float f) {
  __hip_bfloat16 h = __float2bfloat16(f);
  return *(unsigned short*)&h;
}

// ---------------------------------------------------------------------------
// K0a: convert x fp32 -> bf16 (RNE). 8 elems/thread.
// ---------------------------------------------------------------------------
__global__ __launch_bounds__(256) void k_cvt_x(const float* __restrict__ x,
                                               unsigned short* __restrict__ xb) {
  const int i = blockIdx.x * 256 + threadIdx.x;  // 800000 threads exact
  const float4 a = ((const float4*)x)[(size_t)i * 2];
  const float4 b = ((const float4*)x)[(size_t)i * 2 + 1];
  union { unsigned short s[8]; uint4 v; } o;
  o.s[0] = f2bf(a.x); o.s[1] = f2bf(a.y); o.s[2] = f2bf(a.z); o.s[3] = f2bf(a.w);
  o.s[4] = f2bf(b.x); o.s[5] = f2bf(b.y); o.s[6] = f2bf(b.z); o.s[7] = f2bf(b.w);
  ((uint4*)xb)[i] = o.v;
}

// ---------------------------------------------------------------------------
// K0b: WcatT[n][k] = bf16( (n<128 ? Wl : Wr)[k][n&127] )  -- 256x128, 1 block
// ---------------------------------------------------------------------------
__global__ __launch_bounds__(256) void k_cvt_w(const float* __restrict__ Wl,
                                               const float* __restrict__ Wr,
                                               unsigned short* __restrict__ WcatT) {
  const int n = threadIdx.x;
  const float* W = (n < 128) ? Wl : Wr;
  const int col = n & 127;
  for (int k = 0; k < 128; ++k)
    WcatT[n * 128 + k] = f2bf(W[k * HC + col]);
}

// ---------------------------------------------------------------------------
// K1: MFMA GEMM  [50000x128] @ [128x256] -> xl (cols 0-127) / xr (cols 128-255)
// blockIdx.y = 0 -> xl half, 1 -> xr half. Tile 128x128, K=128 in LDS.
// 4 waves, each 64x64 quadrant via 4x4 frags of 16x16x32 bf16 MFMA.
// ---------------------------------------------------------------------------
__global__ __launch_bounds__(256) void k_gemm(
    const unsigned short* __restrict__ xb, const unsigned short* __restrict__ WcatT,
    const float* __restrict__ bl, const float* __restrict__ br,
    unsigned short* __restrict__ xl, unsigned short* __restrict__ xr) {
  __shared__ unsigned short As[128 * 136];  // pad 8: even bank spread for b128
  const int t = threadIdx.x;
  const int m0 = blockIdx.x * 128;
  const int nt = blockIdx.y;

  // stage A tile (guarded tail)
#pragma unroll
  for (int it = 0; it < 8; ++it) {
    const int c = t + it * 256;
    const int row = c >> 4, c8 = (c & 15) * 8;
    uint4 v = make_uint4(0, 0, 0, 0);
    if (m0 + row < N_NODES) v = *(const uint4*)(xb + (size_t)(m0 + row) * HC + c8);
    *(uint4*)(&As[row * 136 + c8]) = v;
  }
  __syncthreads();

  const int w = t >> 6, lane = t & 63;
  const int wm = w >> 1, wn = w & 1;
  const int lr = lane & 15, lk = lane >> 4;

  f32x4 acc[4][4];
#pragma unroll
  for (int i = 0; i < 4; ++i)
#pragma unroll
    for (int j = 0; j < 4; ++j) acc[i][j] = (f32x4)(0.f);

  const unsigned short* Wbase = WcatT + (size_t)(nt * 128 + wn * 64 + lr) * 128;
#pragma unroll
  for (int ks = 0; ks < 4; ++ks) {
    const int k = ks * 32 + lk * 8;
    bf16x8 bfr[4], afr[4];
#pragma unroll
    for (int ni = 0; ni < 4; ++ni)
      bfr[ni] = *(const bf16x8*)(Wbase + ni * 16 * 128 + k);
#pragma unroll
    for (int mi = 0; mi < 4; ++mi)
      afr[mi] = *(const bf16x8*)(&As[(wm * 64 + mi * 16 + lr) * 136 + k]);
#pragma unroll
    for (int mi = 0; mi < 4; ++mi)
#pragma unroll
      for (int ni = 0; ni < 4; ++ni)
        acc[mi][ni] = __builtin_amdgcn_mfma_f32_16x16x32_bf16(
            afr[mi], bfr[ni], acc[mi][ni], 0, 0, 0);
  }

  const float* bvec = nt ? br : bl;
  unsigned short* __restrict__ dst = nt ? xr : xl;
#pragma unroll
  for (int ni = 0; ni < 4; ++ni) {
    const int gcol = wn * 64 + ni * 16 + lr;
    const float bb = bvec[gcol];
#pragma unroll
    for (int mi = 0; mi < 4; ++mi) {
#pragma unroll
      for (int r = 0; r < 4; ++r) {
        const int grow = m0 + wm * 64 + mi * 16 + lk * 4 + r;
        if (grow < N_NODES)
          dst[(size_t)grow * HC + gcol] = f2bf(acc[mi][ni][r] + bb);
      }
    }
  }
}

// ---------------------------------------------------------------------------
// K2a: degree histogram over dst
// ---------------------------------------------------------------------------
__global__ __launch_bounds__(256) void k_deg(const int* __restrict__ eidx,
                                             int* __restrict__ deg) {
  const int e = blockIdx.x * 256 + threadIdx.x;
  if (e < N_EDGES) atomicAdd(&deg[eidx[N_EDGES + e]], 1);
}

// ---------------------------------------------------------------------------
// K2b: single-block scan of degrees -> offs[0..N_NODES]
// ---------------------------------------------------------------------------
__global__ __launch_bounds__(1024) void k_scan(const int* __restrict__ deg,
                                               int* __restrict__ offs) {
  __shared__ int sm[1024];
  const int t = threadIdx.x;
  const int per = (N_NODES + 1023) / 1024;  // 49
  const int base = t * per;
  int s = 0;
  for (int i = 0; i < per; ++i) {
    const int idx = base + i;
    if (idx < N_NODES) s += deg[idx];
  }
  sm[t] = s;
  __syncthreads();
  for (int off = 1; off < 1024; off <<= 1) {
    const int add = (t >= off) ? sm[t - off] : 0;
    __syncthreads();
    sm[t] += add;
    __syncthreads();
  }
  int excl = sm[t] - s;
  for (int i = 0; i < per; ++i) {
    const int idx = base + i;
    if (idx < N_NODES) {
      offs[idx] = excl;
      excl += deg[idx];
    }
  }
  if (t == 1023) offs[N_NODES] = sm[1023];
}

// ---------------------------------------------------------------------------
// K2c: scatter packed edge records {src, ea.x, ea.y, 0} into CSR order
// ---------------------------------------------------------------------------
__global__ __launch_bounds__(256) void k_scatter(
    const int* __restrict__ eidx, const float* __restrict__ eattr,
    const int* __restrict__ offs, int* __restrict__ cursor,
    int4* __restrict__ epack) {
  const int e = blockIdx.x * 256 + threadIdx.x;
  if (e < N_EDGES) {
    const int src = eidx[e];
    const int d = eidx[N_EDGES + e];
    const float2 ea = *(const float2*)(eattr + (size_t)e * 2);
    const int pos = atomicAdd(&cursor[d], 1);
    epack[offs[d] + pos] =
        make_int4(src, __float_as_int(ea.x), __float_as_int(ea.y), 0);
  }
}

// ---------------------------------------------------------------------------
// K3: merged attention + aggregation. One wave per node; lane owns 2 channels
// (c0=2*lane, head=lane>>3). Per edge: one 256B xl-row gather serves BOTH the
// logit (8-lane shfl reduce per head) and the numerator. 2-stage prefetch:
// epack batch b+2 and xl batch b+1 in flight while consuming batch b.
// ---------------------------------------------------------------------------
__global__ __launch_bounds__(256) void k_attagg(
    const int* __restrict__ offs, const int4* __restrict__ epack,
    const unsigned short* __restrict__ xl, const unsigned short* __restrict__ xr,
    const float* __restrict__ We, const float* __restrict__ be,
    const float* __restrict__ att, float* __restrict__ outp) {
  const int wave = threadIdx.x >> 6, lane = threadIdx.x & 63;
  const int node = blockIdx.x * 4 + wave;  // grid exact: 12500*4 = 50000
  const int c0 = lane * 2;

  const float w0a = We[c0],      w0b = We[c0 + 1];
  const float w1a = We[HC + c0], w1b = We[HC + c0 + 1];
  const float bea = be[c0],      beb = be[c0 + 1];
  const float ata = att[c0],     atb = att[c0 + 1];

  const unsigned int xrw = *((const unsigned int*)(xr + (size_t)node * HC) + lane);
  const float xra = bf2f((unsigned short)xrw);
  const float xrb = bf2f((unsigned short)(xrw >> 16));

  const int beg = offs[node], end = offs[node + 1];
  float dn = 0.f, a0 = 0.f, a1 = 0.f;

  if (beg < end) {
    const int endm1 = end - 1;
    const int nb = (end - beg + 3) >> 2;
    int4 ep0[4], ep1[4];
    unsigned int xw0[4];
#pragma unroll
    for (int j = 0; j < 4; ++j) {
      int kk = beg + j; kk = kk < endm1 ? kk : endm1;
      ep0[j] = epack[kk];
    }
#pragma unroll
    for (int j = 0; j < 4; ++j)
      xw0[j] = *((const unsigned int*)(xl + (size_t)ep0[j].x * HC) + lane);
    if (nb > 1) {
#pragma unroll
      for (int j = 0; j < 4; ++j) {
        int kk = beg + 4 + j; kk = kk < endm1 ? kk : endm1;
        ep1[j] = epack[kk];
      }
    }
    for (int b = 0; b < nb; ++b) {
      unsigned int xw1[4];
      int4 ep2[4];
      if (b + 1 < nb) {  // wave-uniform
#pragma unroll
        for (int j = 0; j < 4; ++j)
          xw1[j] = *((const unsigned int*)(xl + (size_t)ep1[j].x * HC) + lane);
      }
      if (b + 2 < nb) {
#pragma unroll
        for (int j = 0; j < 4; ++j) {
          int kk = beg + (b + 2) * 4 + j; kk = kk < endm1 ? kk : endm1;
          ep2[j] = epack[kk];
        }
      }
      const int k0 = beg + b * 4;
#pragma unroll
      for (int j = 0; j < 4; ++j) {
        const float eax = __int_as_float(ep0[j].y);
        const float eay = __int_as_float(ep0[j].z);
        const float x0 = bf2f((unsigned short)xw0[j]);
        const float x1 = bf2f((unsigned short)(xw0[j] >> 16));
        float m0 = x0 + xra + fmaf(eax, w0a, fmaf(eay, w1a, bea));
        float m1 = x1 + xrb + fmaf(eax, w0b, fmaf(eay, w1b, beb));
        m0 = m0 > 0.f ? m0 : 0.2f * m0;
        m1 = m1 > 0.f ? m1 : 0.2f * m1;
        float p = fmaf(m0, ata, m1 * atb);
        p += __shfl_xor(p, 1);
        p += __shfl_xor(p, 2);
        p += __shfl_xor(p, 4);  // head-group (8 lanes) reduce
        const float exv = (k0 + j < end) ? __expf(p) : 0.f;
        dn += exv;
        a0 = fmaf(exv, x0, a0);
        a1 = fmaf(exv, x1, a1);
      }
#pragma unroll
      for (int j = 0; j < 4; ++j) { ep0[j] = ep1[j]; xw0[j] = xw1[j]; ep1[j] = ep2[j]; }
    }
  }
  const float inv = dn > 0.f ? 1.0f / dn : 0.f;
  float2 o;
  o.x = a0 * inv;
  o.y = a1 * inv;
  *((float2*)(outp + (size_t)node * HC) + lane) = o;
}

// ---------------------------------------------------------------------------
// K4: per-channel sum / sumsq over nodes (BatchNorm batch stats)
// ---------------------------------------------------------------------------
__global__ __launch_bounds__(256) void k_stats(const float* __restrict__ outp,
                                               float* __restrict__ stats) {
  const int c = threadIdx.x & 127;
  const int half = threadIdx.x >> 7;
  float s1 = 0.f, s2 = 0.f;
  for (int r = blockIdx.x * 2 + half; r < N_NODES; r += gridDim.x * 2) {
    const float v = outp[(size_t)r * HC + c];
    s1 += v;
    s2 = fmaf(v, v, s2);
  }
  __shared__ float sm[512];
  sm[threadIdx.x] = s1;
  sm[256 + threadIdx.x] = s2;
  __syncthreads();
  if (threadIdx.x < 128) {
    s1 = sm[threadIdx.x] + sm[threadIdx.x + 128];
    s2 = sm[256 + threadIdx.x] + sm[256 + threadIdx.x + 128];
    atomicAdd(&stats[c], s1);
    atomicAdd(&stats[128 + c], s2);
  }
}

// ---------------------------------------------------------------------------
// K5: BatchNorm (batch stats) + LeakyReLU(0.01), in place on outp
// ---------------------------------------------------------------------------
__global__ __launch_bounds__(256) void k_bn(const float* __restrict__ stats,
                                            const float* __restrict__ gamma,
                                            const float* __restrict__ beta,
                                            float* __restrict__ outp) {
  const int i = blockIdx.x * 256 + threadIdx.x;
  if (i >= N_NODES * HC) return;
  const int c = i & 127;
  const float mean = stats[c] * (1.0f / N_NODES);
  const float var = stats[128 + c] * (1.0f / N_NODES) - mean * mean;
  const float rstd = rsqrtf(var + 1e-5f);
  float v = (outp[i] - mean) * rstd * gamma[c] + beta[c];
  outp[i] = v > 0.f ? v : 0.01f * v;
}

// ---------------------------------------------------------------------------
extern "C" void kernel_launch(void* const* d_in, const int* in_sizes, int n_in,
                              void* d_out, int out_size, void* d_ws, size_t ws_size,
                              hipStream_t stream) {
  const float* x     = (const float*)d_in[0];
  const int*   eidx  = (const int*)d_in[1];
  const float* eattr = (const float*)d_in[2];
  const float* Wl    = (const float*)d_in[3];
  const float* bl    = (const float*)d_in[4];
  const float* Wr    = (const float*)d_in[5];
  const float* br    = (const float*)d_in[6];
  const float* We    = (const float*)d_in[7];
  const float* be    = (const float*)d_in[8];
  const float* att   = (const float*)d_in[9];
  // d_in[10] = bias: cancels exactly in BatchNorm mean subtraction -> unused
  const float* gamma = (const float*)d_in[11];
  const float* beta  = (const float*)d_in[12];
  float* out = (float*)d_out;

  char* ws = (char*)d_ws;
  size_t off = 0;
  auto alloc = [&](size_t bytes) {
    size_t o = off;
    off = (off + bytes + 15) & ~size_t(15);
    return o;
  };
  // zero-initialized region first
  const size_t o_deg   = alloc((size_t)(N_NODES + 1) * 4);
  const size_t o_cur   = alloc((size_t)N_NODES * 4);
  const size_t o_stats = alloc(256 * 4);
  const size_t zero_bytes = off;
  // non-zeroed scratch
  const size_t o_offs = alloc((size_t)(N_NODES + 1) * 4);
  const size_t o_ep   = alloc((size_t)N_EDGES * 16);
  const size_t o_xb   = alloc((size_t)N_NODES * HC * 2);
  const size_t o_wt   = alloc((size_t)256 * 128 * 2);
  const size_t o_xl   = alloc((size_t)N_NODES * HC * 2);
  const size_t o_xr   = alloc((size_t)N_NODES * HC * 2);
  (void)ws_size; (void)in_sizes; (void)n_in; (void)out_size;

  int*   deg   = (int*)(ws + o_deg);
  int*   cur   = (int*)(ws + o_cur);
  float* stats = (float*)(ws + o_stats);
  int*   offs  = (int*)(ws + o_offs);
  int4*  epack = (int4*)(ws + o_ep);
  unsigned short* xb    = (unsigned short*)(ws + o_xb);
  unsigned short* WcatT = (unsigned short*)(ws + o_wt);
  unsigned short* xl    = (unsigned short*)(ws + o_xl);
  unsigned short* xr    = (unsigned short*)(ws + o_xr);

  hipMemsetAsync(ws, 0, zero_bytes, stream);

  k_cvt_x<<<3125, 256, 0, stream>>>(x, xb);
  k_cvt_w<<<1, 256, 0, stream>>>(Wl, Wr, WcatT);
  k_gemm<<<dim3(391, 2), 256, 0, stream>>>(xb, WcatT, bl, br, xl, xr);
  k_deg<<<3125, 256, 0, stream>>>(eidx, deg);
  k_scan<<<1, 1024, 0, stream>>>(deg, offs);
  k_scatter<<<3125, 256, 0, stream>>>(eidx, eattr, offs, cur, epack);
  k_attagg<<<12500, 256, 0, stream>>>(offs, epack, xl, xr, We, be, att, out);
  k_stats<<<256, 256, 0, stream>>>(out, stats);
  k_bn<<<25000, 256, 0, stream>>>(stats, gamma, beta, out);
}

// Round 6
// 346.901 us; speedup vs baseline: 2.6716x; 1.2589x over previous
//
#include <hip/hip_runtime.h>
#include <hip/hip_bf16.h>

#define N_NODES 50000
#define N_EDGES 800000
#define HEADS 8
#define HID 16
#define HC 128  // HEADS*HID

typedef __attribute__((ext_vector_type(8))) short bf16x8;
typedef __attribute__((ext_vector_type(4))) float f32x4;

__device__ __forceinline__ float bf2f(unsigned short u) {
  union { unsigned int i; float f; } v;
  v.i = (unsigned int)u << 16;
  return v.f;
}
__device__ __forceinline__ unsigned short f2bf(float f) {
  __hip_bfloat16 h = __float2bfloat16(f);
  return *(unsigned short*)&h;
}

// ---------------------------------------------------------------------------
// K0a: convert x fp32 -> bf16 (RNE). 8 elems/thread.
// ---------------------------------------------------------------------------
__global__ __launch_bounds__(256) void k_cvt_x(const float* __restrict__ x,
                                               unsigned short* __restrict__ xb) {
  const int i = blockIdx.x * 256 + threadIdx.x;  // 800000 threads exact
  const float4 a = ((const float4*)x)[(size_t)i * 2];
  const float4 b = ((const float4*)x)[(size_t)i * 2 + 1];
  union { unsigned short s[8]; uint4 v; } o;
  o.s[0] = f2bf(a.x); o.s[1] = f2bf(a.y); o.s[2] = f2bf(a.z); o.s[3] = f2bf(a.w);
  o.s[4] = f2bf(b.x); o.s[5] = f2bf(b.y); o.s[6] = f2bf(b.z); o.s[7] = f2bf(b.w);
  ((uint4*)xb)[i] = o.v;
}

// ---------------------------------------------------------------------------
// K0b: WcatT[n][k] = bf16( (n<128 ? Wl : Wr)[k][n&127] )
// grid 256 (n), 128 threads (k): coalesced writes along k.
// ---------------------------------------------------------------------------
__global__ __launch_bounds__(128) void k_cvt_w(const float* __restrict__ Wl,
                                               const float* __restrict__ Wr,
                                               unsigned short* __restrict__ WcatT) {
  const int n = blockIdx.x;
  const int k = threadIdx.x;
  const float* W = (n < 128) ? Wl : Wr;
  WcatT[n * 128 + k] = f2bf(W[k * HC + (n & 127)]);
}

// ---------------------------------------------------------------------------
// K1: MFMA GEMM  [50000x128] @ [128x256] -> xl (cols 0-127) / xr (cols 128-255)
// ---------------------------------------------------------------------------
__global__ __launch_bounds__(256) void k_gemm(
    const unsigned short* __restrict__ xb, const unsigned short* __restrict__ WcatT,
    const float* __restrict__ bl, const float* __restrict__ br,
    unsigned short* __restrict__ xl, unsigned short* __restrict__ xr) {
  __shared__ unsigned short As[128 * 136];  // pad 8: even bank spread for b128
  const int t = threadIdx.x;
  const int m0 = blockIdx.x * 128;
  const int nt = blockIdx.y;

#pragma unroll
  for (int it = 0; it < 8; ++it) {
    const int c = t + it * 256;
    const int row = c >> 4, c8 = (c & 15) * 8;
    uint4 v = make_uint4(0, 0, 0, 0);
    if (m0 + row < N_NODES) v = *(const uint4*)(xb + (size_t)(m0 + row) * HC + c8);
    *(uint4*)(&As[row * 136 + c8]) = v;
  }
  __syncthreads();

  const int w = t >> 6, lane = t & 63;
  const int wm = w >> 1, wn = w & 1;
  const int lr = lane & 15, lk = lane >> 4;

  f32x4 acc[4][4];
#pragma unroll
  for (int i = 0; i < 4; ++i)
#pragma unroll
    for (int j = 0; j < 4; ++j) acc[i][j] = (f32x4)(0.f);

  const unsigned short* Wbase = WcatT + (size_t)(nt * 128 + wn * 64 + lr) * 128;
#pragma unroll
  for (int ks = 0; ks < 4; ++ks) {
    const int k = ks * 32 + lk * 8;
    bf16x8 bfr[4], afr[4];
#pragma unroll
    for (int ni = 0; ni < 4; ++ni)
      bfr[ni] = *(const bf16x8*)(Wbase + ni * 16 * 128 + k);
#pragma unroll
    for (int mi = 0; mi < 4; ++mi)
      afr[mi] = *(const bf16x8*)(&As[(wm * 64 + mi * 16 + lr) * 136 + k]);
#pragma unroll
    for (int mi = 0; mi < 4; ++mi)
#pragma unroll
      for (int ni = 0; ni < 4; ++ni)
        acc[mi][ni] = __builtin_amdgcn_mfma_f32_16x16x32_bf16(
            afr[mi], bfr[ni], acc[mi][ni], 0, 0, 0);
  }

  const float* bvec = nt ? br : bl;
  unsigned short* __restrict__ dst = nt ? xr : xl;
#pragma unroll
  for (int ni = 0; ni < 4; ++ni) {
    const int gcol = wn * 64 + ni * 16 + lr;
    const float bb = bvec[gcol];
#pragma unroll
    for (int mi = 0; mi < 4; ++mi) {
#pragma unroll
      for (int r = 0; r < 4; ++r) {
        const int grow = m0 + wm * 64 + mi * 16 + lk * 4 + r;
        if (grow < N_NODES)
          dst[(size_t)grow * HC + gcol] = f2bf(acc[mi][ni][r] + bb);
      }
    }
  }
}

// ---------------------------------------------------------------------------
// K2a: degree histogram over dst
// ---------------------------------------------------------------------------
__global__ __launch_bounds__(256) void k_deg(const int* __restrict__ eidx,
                                             int* __restrict__ deg) {
  const int e = blockIdx.x * 256 + threadIdx.x;
  if (e < N_EDGES) atomicAdd(&deg[eidx[N_EDGES + e]], 1);
}

// ---------------------------------------------------------------------------
// K2b: parallel CSR region allocation (replaces single-block scan).
// Wave-level prefix sum of degrees + one atomicAdd per wave on a global
// counter. offs[] is NOT monotonic across waves -- only disjoint+contiguous
// per node, which is all k_scatter/k_attagg need (end = beg + deg[node]).
// ---------------------------------------------------------------------------
__global__ __launch_bounds__(256) void k_alloc(const int* __restrict__ deg,
                                               int* __restrict__ counter,
                                               int* __restrict__ offs) {
  const int node = blockIdx.x * 256 + threadIdx.x;
  const int lane = threadIdx.x & 63;
  const int v = (node < N_NODES) ? deg[node] : 0;
  int incl = v;
#pragma unroll
  for (int d = 1; d < 64; d <<= 1) {
    const int t = __shfl_up(incl, d);
    if (lane >= d) incl += t;
  }
  const int total = __shfl(incl, 63);
  int base = 0;
  if (lane == 63) base = atomicAdd(counter, total);
  base = __shfl(base, 63);
  if (node < N_NODES) offs[node] = base + incl - v;
}

// ---------------------------------------------------------------------------
// K2c: scatter packed edge records {src, ea.x, ea.y, 0} into CSR order
// ---------------------------------------------------------------------------
__global__ __launch_bounds__(256) void k_scatter(
    const int* __restrict__ eidx, const float* __restrict__ eattr,
    const int* __restrict__ offs, int* __restrict__ cursor,
    int4* __restrict__ epack) {
  const int e = blockIdx.x * 256 + threadIdx.x;
  if (e < N_EDGES) {
    const int src = eidx[e];
    const int d = eidx[N_EDGES + e];
    const float2 ea = *(const float2*)(eattr + (size_t)e * 2);
    const int pos = atomicAdd(&cursor[d], 1);
    epack[offs[d] + pos] =
        make_int4(src, __float_as_int(ea.x), __float_as_int(ea.y), 0);
  }
}

// ---------------------------------------------------------------------------
// K3: merged attention + aggregation. One wave per node; lane owns 2 channels
// (c0=2*lane, head=lane>>3). Per edge: one 256B xl-row gather serves BOTH the
// logit (8-lane shfl reduce per head) and the numerator. 2-stage prefetch.
// ---------------------------------------------------------------------------
__global__ __launch_bounds__(256) void k_attagg(
    const int* __restrict__ offs, const int* __restrict__ deg,
    const int4* __restrict__ epack,
    const unsigned short* __restrict__ xl, const unsigned short* __restrict__ xr,
    const float* __restrict__ We, const float* __restrict__ be,
    const float* __restrict__ att, float* __restrict__ outp) {
  const int wave = threadIdx.x >> 6, lane = threadIdx.x & 63;
  const int node = blockIdx.x * 4 + wave;  // grid exact: 12500*4 = 50000
  const int c0 = lane * 2;

  const float w0a = We[c0],      w0b = We[c0 + 1];
  const float w1a = We[HC + c0], w1b = We[HC + c0 + 1];
  const float bea = be[c0],      beb = be[c0 + 1];
  const float ata = att[c0],     atb = att[c0 + 1];

  const unsigned int xrw = *((const unsigned int*)(xr + (size_t)node * HC) + lane);
  const float xra = bf2f((unsigned short)xrw);
  const float xrb = bf2f((unsigned short)(xrw >> 16));

  const int beg = offs[node];
  const int end = beg + deg[node];
  float dn = 0.f, a0 = 0.f, a1 = 0.f;

  if (beg < end) {
    const int endm1 = end - 1;
    const int nb = (end - beg + 3) >> 2;
    int4 ep0[4], ep1[4];
    unsigned int xw0[4];
#pragma unroll
    for (int j = 0; j < 4; ++j) {
      int kk = beg + j; kk = kk < endm1 ? kk : endm1;
      ep0[j] = epack[kk];
    }
#pragma unroll
    for (int j = 0; j < 4; ++j)
      xw0[j] = *((const unsigned int*)(xl + (size_t)ep0[j].x * HC) + lane);
    if (nb > 1) {
#pragma unroll
      for (int j = 0; j < 4; ++j) {
        int kk = beg + 4 + j; kk = kk < endm1 ? kk : endm1;
        ep1[j] = epack[kk];
      }
    }
    for (int b = 0; b < nb; ++b) {
      unsigned int xw1[4];
      int4 ep2[4];
      if (b + 1 < nb) {  // wave-uniform
#pragma unroll
        for (int j = 0; j < 4; ++j)
          xw1[j] = *((const unsigned int*)(xl + (size_t)ep1[j].x * HC) + lane);
      }
      if (b + 2 < nb) {
#pragma unroll
        for (int j = 0; j < 4; ++j) {
          int kk = beg + (b + 2) * 4 + j; kk = kk < endm1 ? kk : endm1;
          ep2[j] = epack[kk];
        }
      }
      const int k0 = beg + b * 4;
#pragma unroll
      for (int j = 0; j < 4; ++j) {
        const float eax = __int_as_float(ep0[j].y);
        const float eay = __int_as_float(ep0[j].z);
        const float x0 = bf2f((unsigned short)xw0[j]);
        const float x1 = bf2f((unsigned short)(xw0[j] >> 16));
        float m0 = x0 + xra + fmaf(eax, w0a, fmaf(eay, w1a, bea));
        float m1 = x1 + xrb + fmaf(eax, w0b, fmaf(eay, w1b, beb));
        m0 = m0 > 0.f ? m0 : 0.2f * m0;
        m1 = m1 > 0.f ? m1 : 0.2f * m1;
        float p = fmaf(m0, ata, m1 * atb);
        p += __shfl_xor(p, 1);
        p += __shfl_xor(p, 2);
        p += __shfl_xor(p, 4);  // head-group (8 lanes) reduce
        const float exv = (k0 + j < end) ? __expf(p) : 0.f;
        dn += exv;
        a0 = fmaf(exv, x0, a0);
        a1 = fmaf(exv, x1, a1);
      }
#pragma unroll
      for (int j = 0; j < 4; ++j) { ep0[j] = ep1[j]; xw0[j] = xw1[j]; ep1[j] = ep2[j]; }
    }
  }
  const float inv = dn > 0.f ? 1.0f / dn : 0.f;
  float2 o;
  o.x = a0 * inv;
  o.y = a1 * inv;
  *((float2*)(outp + (size_t)node * HC) + lane) = o;
}

// ---------------------------------------------------------------------------
// K4: per-channel sum / sumsq over nodes (BatchNorm batch stats)
// ---------------------------------------------------------------------------
__global__ __launch_bounds__(256) void k_stats(const float* __restrict__ outp,
                                               float* __restrict__ stats) {
  const int c = threadIdx.x & 127;
  const int half = threadIdx.x >> 7;
  float s1 = 0.f, s2 = 0.f;
  for (int r = blockIdx.x * 2 + half; r < N_NODES; r += gridDim.x * 2) {
    const float v = outp[(size_t)r * HC + c];
    s1 += v;
    s2 = fmaf(v, v, s2);
  }
  __shared__ float sm[512];
  sm[threadIdx.x] = s1;
  sm[256 + threadIdx.x] = s2;
  __syncthreads();
  if (threadIdx.x < 128) {
    s1 = sm[threadIdx.x] + sm[threadIdx.x + 128];
    s2 = sm[256 + threadIdx.x] + sm[256 + threadIdx.x + 128];
    atomicAdd(&stats[c], s1);
    atomicAdd(&stats[128 + c], s2);
  }
}

// ---------------------------------------------------------------------------
// K5: BatchNorm (batch stats) + LeakyReLU(0.01), in place on outp
// ---------------------------------------------------------------------------
__global__ __launch_bounds__(256) void k_bn(const float* __restrict__ stats,
                                            const float* __restrict__ gamma,
                                            const float* __restrict__ beta,
                                            float* __restrict__ outp) {
  const int i = blockIdx.x * 256 + threadIdx.x;
  if (i >= N_NODES * HC) return;
  const int c = i & 127;
  const float mean = stats[c] * (1.0f / N_NODES);
  const float var = stats[128 + c] * (1.0f / N_NODES) - mean * mean;
  const float rstd = rsqrtf(var + 1e-5f);
  float v = (outp[i] - mean) * rstd * gamma[c] + beta[c];
  outp[i] = v > 0.f ? v : 0.01f * v;
}

// ---------------------------------------------------------------------------
extern "C" void kernel_launch(void* const* d_in, const int* in_sizes, int n_in,
                              void* d_out, int out_size, void* d_ws, size_t ws_size,
                              hipStream_t stream) {
  const float* x     = (const float*)d_in[0];
  const int*   eidx  = (const int*)d_in[1];
  const float* eattr = (const float*)d_in[2];
  const float* Wl    = (const float*)d_in[3];
  const float* bl    = (const float*)d_in[4];
  const float* Wr    = (const float*)d_in[5];
  const float* br    = (const float*)d_in[6];
  const float* We    = (const float*)d_in[7];
  const float* be    = (const float*)d_in[8];
  const float* att   = (const float*)d_in[9];
  // d_in[10] = bias: cancels exactly in BatchNorm mean subtraction -> unused
  const float* gamma = (const float*)d_in[11];
  const float* beta  = (const float*)d_in[12];
  float* out = (float*)d_out;

  char* ws = (char*)d_ws;
  size_t off = 0;
  auto alloc = [&](size_t bytes) {
    size_t o = off;
    off = (off + bytes + 15) & ~size_t(15);
    return o;
  };
  // zero-initialized region first
  const size_t o_deg   = alloc((size_t)(N_NODES + 1) * 4);
  const size_t o_cur   = alloc((size_t)N_NODES * 4);
  const size_t o_cnt   = alloc(16);
  const size_t o_stats = alloc(256 * 4);
  const size_t zero_bytes = off;
  // non-zeroed scratch
  const size_t o_offs = alloc((size_t)(N_NODES + 1) * 4);
  const size_t o_ep   = alloc((size_t)N_EDGES * 16);
  const size_t o_xb   = alloc((size_t)N_NODES * HC * 2);
  const size_t o_wt   = alloc((size_t)256 * 128 * 2);
  const size_t o_xl   = alloc((size_t)N_NODES * HC * 2);
  const size_t o_xr   = alloc((size_t)N_NODES * HC * 2);
  (void)ws_size; (void)in_sizes; (void)n_in; (void)out_size;

  int*   deg   = (int*)(ws + o_deg);
  int*   cur   = (int*)(ws + o_cur);
  int*   cnt   = (int*)(ws + o_cnt);
  float* stats = (float*)(ws + o_stats);
  int*   offs  = (int*)(ws + o_offs);
  int4*  epack = (int4*)(ws + o_ep);
  unsigned short* xb    = (unsigned short*)(ws + o_xb);
  unsigned short* WcatT = (unsigned short*)(ws + o_wt);
  unsigned short* xl    = (unsigned short*)(ws + o_xl);
  unsigned short* xr    = (unsigned short*)(ws + o_xr);

  hipMemsetAsync(ws, 0, zero_bytes, stream);

  k_cvt_x<<<3125, 256, 0, stream>>>(x, xb);
  k_cvt_w<<<256, 128, 0, stream>>>(Wl, Wr, WcatT);
  k_gemm<<<dim3(391, 2), 256, 0, stream>>>(xb, WcatT, bl, br, xl, xr);
  k_deg<<<3125, 256, 0, stream>>>(eidx, deg);
  k_alloc<<<196, 256, 0, stream>>>(deg, cnt, offs);
  k_scatter<<<3125, 256, 0, stream>>>(eidx, eattr, offs, cur, epack);
  k_attagg<<<12500, 256, 0, stream>>>(offs, deg, epack, xl, xr, We, be, att, out);
  k_stats<<<256, 256, 0, stream>>>(out, stats);
  k_bn<<<25000, 256, 0, stream>>>(stats, gamma, beta, out);
}

// Round 7
// 296.273 us; speedup vs baseline: 3.1281x; 1.1709x over previous
//
#include <hip/hip_runtime.h>
#include <hip/hip_bf16.h>

#define N_NODES 50000
#define N_EDGES 800000
#define HEADS 8
#define HID 16
#define HC 128  // HEADS*HID

typedef __attribute__((ext_vector_type(8))) short bf16x8;
typedef __attribute__((ext_vector_type(4))) float f32x4;

__device__ __forceinline__ float bf2f(unsigned short u) {
  union { unsigned int i; float f; } v;
  v.i = (unsigned int)u << 16;
  return v.f;
}
__device__ __forceinline__ unsigned short f2bf(float f) {
  __hip_bfloat16 h = __float2bfloat16(f);
  return *(unsigned short*)&h;
}

// ---------------------------------------------------------------------------
// K1: prep = [blocks 0..3124] degree histogram  U  [3125..3252] W transpose.
// WcatT[n][k] = bf16( (n<128 ? Wl : Wr)[k][n&127] ), n in [0,256), k in [0,128)
// ---------------------------------------------------------------------------
__global__ __launch_bounds__(256) void k_prep(
    const int* __restrict__ eidx, const float* __restrict__ Wl,
    const float* __restrict__ Wr, int* __restrict__ deg,
    unsigned short* __restrict__ WcatT) {
  const int b = blockIdx.x;
  if (b < 3125) {
    const int e = b * 256 + threadIdx.x;  // 800000 exact
    atomicAdd(&deg[eidx[N_EDGES + e]], 1);
  } else {
    const int idx = (b - 3125) * 256 + threadIdx.x;  // < 32768
    const int n = idx >> 7, k = idx & 127;
    const float* W = (n < 128) ? Wl : Wr;
    WcatT[idx] = f2bf(W[k * HC + (n & 127)]);
  }
}

// ---------------------------------------------------------------------------
// K2: [blocks 0..390] MFMA GEMM: x(fp32, converted in staging) @ [Wl|Wr]
//     -> xl/xr bf16. 8 waves: (wm,wn) = (w>>2, w&3), 64x64 out each.
//     [blocks 391..488] CSR region allocation (wave prefix-scan + atomic).
// ---------------------------------------------------------------------------
__global__ __launch_bounds__(512) void k_gemm_alloc(
    const float* __restrict__ x, const unsigned short* __restrict__ WcatT,
    const float* __restrict__ bl, const float* __restrict__ br,
    unsigned short* __restrict__ xl, unsigned short* __restrict__ xr,
    const int* __restrict__ deg, int* __restrict__ counter,
    int* __restrict__ offs) {
  __shared__ unsigned short As[128 * 136];  // pad 8 shorts: bank spread
  const int t = threadIdx.x;

  if (blockIdx.x >= 391) {  // ---- CSR alloc part ----
    const int node = (blockIdx.x - 391) * 512 + t;  // 98*512 = 50176
    const int lane = t & 63;
    const int v = (node < N_NODES) ? deg[node] : 0;
    int incl = v;
#pragma unroll
    for (int d = 1; d < 64; d <<= 1) {
      const int tt = __shfl_up(incl, d);
      if (lane >= d) incl += tt;
    }
    const int total = __shfl(incl, 63);
    int base = 0;
    if (lane == 63) base = atomicAdd(counter, total);
    base = __shfl(base, 63);
    if (node < N_NODES) offs[node] = base + incl - v;
    return;
  }

  // ---- GEMM part ----
  const int m0 = blockIdx.x * 128;
  // stage 128x128 fp32 -> bf16 LDS (2048 8-float chunks, 4 per thread)
#pragma unroll
  for (int it = 0; it < 4; ++it) {
    const int c = t + it * 512;
    const int row = c >> 4;
    const int seg = (c & 15) * 8;
    const int grow = m0 + row;
    float4 a = make_float4(0.f, 0.f, 0.f, 0.f), bb2 = a;
    if (grow < N_NODES) {
      const float4* p = (const float4*)(x + (size_t)grow * 128 + seg);
      a = p[0];
      bb2 = p[1];
    }
    union { unsigned short s[8]; uint4 v; } o;
    o.s[0] = f2bf(a.x);   o.s[1] = f2bf(a.y);
    o.s[2] = f2bf(a.z);   o.s[3] = f2bf(a.w);
    o.s[4] = f2bf(bb2.x); o.s[5] = f2bf(bb2.y);
    o.s[6] = f2bf(bb2.z); o.s[7] = f2bf(bb2.w);
    *(uint4*)(&As[row * 136 + seg]) = o.v;
  }
  __syncthreads();

  const int w = t >> 6, lane = t & 63;
  const int wm = w >> 2, wn = w & 3;
  const int lr = lane & 15, lk = lane >> 4;

  f32x4 acc[4][4];
#pragma unroll
  for (int i = 0; i < 4; ++i)
#pragma unroll
    for (int j = 0; j < 4; ++j) acc[i][j] = (f32x4)(0.f);

  const unsigned short* Wbase = WcatT + (size_t)(wn * 64 + lr) * 128;
#pragma unroll
  for (int ks = 0; ks < 4; ++ks) {
    const int k = ks * 32 + lk * 8;
    bf16x8 bfr[4], afr[4];
#pragma unroll
    for (int ni = 0; ni < 4; ++ni)
      bfr[ni] = *(const bf16x8*)(Wbase + ni * 16 * 128 + k);
#pragma unroll
    for (int mi = 0; mi < 4; ++mi)
      afr[mi] = *(const bf16x8*)(&As[(wm * 64 + mi * 16 + lr) * 136 + k]);
#pragma unroll
    for (int mi = 0; mi < 4; ++mi)
#pragma unroll
      for (int ni = 0; ni < 4; ++ni)
        acc[mi][ni] = __builtin_amdgcn_mfma_f32_16x16x32_bf16(
            afr[mi], bfr[ni], acc[mi][ni], 0, 0, 0);
  }

#pragma unroll
  for (int ni = 0; ni < 4; ++ni) {
    const int gcol = wn * 64 + ni * 16 + lr;  // 0..255
    const bool left = gcol < 128;
    const float bb = left ? bl[gcol] : br[gcol - 128];
    unsigned short* __restrict__ dst = left ? xl : xr;
    const int cc = gcol & 127;
#pragma unroll
    for (int mi = 0; mi < 4; ++mi) {
#pragma unroll
      for (int r = 0; r < 4; ++r) {
        const int grow = m0 + wm * 64 + mi * 16 + lk * 4 + r;
        if (grow < N_NODES) dst[(size_t)grow * HC + cc] = f2bf(acc[mi][ni][r] + bb);
      }
    }
  }
}

// ---------------------------------------------------------------------------
// K3: scatter packed edge records {src, ea.x, ea.y, 0} into CSR order
// ---------------------------------------------------------------------------
__global__ __launch_bounds__(256) void k_scatter(
    const int* __restrict__ eidx, const float* __restrict__ eattr,
    const int* __restrict__ offs, int* __restrict__ cursor,
    int4* __restrict__ epack) {
  const int e = blockIdx.x * 256 + threadIdx.x;  // 800000 exact
  const int src = eidx[e];
  const int d = eidx[N_EDGES + e];
  const float2 ea = *(const float2*)(eattr + (size_t)e * 2);
  const int pos = atomicAdd(&cursor[d], 1);
  epack[offs[d] + pos] = make_int4(src, __float_as_int(ea.x), __float_as_int(ea.y), 0);
}

// ---------------------------------------------------------------------------
// K4: merged attention + aggregation + BN partial stats.
// One wave per node; lane owns channels (2*lane, 2*lane+1), head = lane>>3.
// Full batches of 4 edges run guard/clamp-free with 2-stage prefetch;
// <=3 tail edges handled separately. Epilogue: LDS reduce -> 8-bucket atomics.
// ---------------------------------------------------------------------------
#define LOADB(EP, K)                                   \
  _Pragma("unroll") for (int j = 0; j < 4; ++j) EP[j] = epack[(K) + j];
#define LOADX(XW, EP)                                  \
  _Pragma("unroll") for (int j = 0; j < 4; ++j)        \
      XW[j] = *((const unsigned int*)(xl + (size_t)EP[j].x * HC) + lane);
#define EDGE1(EPJ, XWJ)                                                     \
  {                                                                         \
    const float eax = __int_as_float((EPJ).y);                              \
    const float eay = __int_as_float((EPJ).z);                              \
    const float x0 = bf2f((unsigned short)(XWJ));                           \
    const float x1 = bf2f((unsigned short)((XWJ) >> 16));                   \
    float m0 = fmaf(eax, w0a, fmaf(eay, w1a, ca)) + x0;                     \
    float m1 = fmaf(eax, w0b, fmaf(eay, w1b, cb)) + x1;                     \
    m0 = fmaxf(m0, 0.2f * m0);                                              \
    m1 = fmaxf(m1, 0.2f * m1);                                              \
    float p = fmaf(m0, ata, m1 * atb);                                      \
    p += __shfl_xor(p, 1);                                                  \
    p += __shfl_xor(p, 2);                                                  \
    p += __shfl_xor(p, 4);                                                  \
    const float exv = __expf(p);                                            \
    dn += exv;                                                              \
    a0 = fmaf(exv, x0, a0);                                                 \
    a1 = fmaf(exv, x1, a1);                                                 \
  }
#define COMPUTE4(EP, XW)                               \
  _Pragma("unroll") for (int j = 0; j < 4; ++j) EDGE1(EP[j], XW[j])

__global__ __launch_bounds__(256) void k_attagg(
    const int* __restrict__ offs, const int* __restrict__ deg,
    const int4* __restrict__ epack,
    const unsigned short* __restrict__ xl, const unsigned short* __restrict__ xr,
    const float* __restrict__ We, const float* __restrict__ be,
    const float* __restrict__ att, float* __restrict__ outp,
    float* __restrict__ statsB) {
  __shared__ float ssum[4 * 128];
  __shared__ float ssq[4 * 128];
  const int wave = threadIdx.x >> 6, lane = threadIdx.x & 63;
  const int node = blockIdx.x * 4 + wave;  // 12500*4 = 50000 exact
  const int c0 = lane * 2;

  const float w0a = We[c0],      w0b = We[c0 + 1];
  const float w1a = We[HC + c0], w1b = We[HC + c0 + 1];
  const float ata = att[c0],     atb = att[c0 + 1];

  const unsigned int xrw = *((const unsigned int*)(xr + (size_t)node * HC) + lane);
  const float ca = be[c0] + bf2f((unsigned short)xrw);
  const float cb = be[c0 + 1] + bf2f((unsigned short)(xrw >> 16));

  const int beg = offs[node];
  const int dn_e = deg[node];
  const int end = beg + dn_e;
  const int nf = dn_e >> 2;  // full batches of 4

  float dn = 0.f, a0 = 0.f, a1 = 0.f;

  if (nf >= 1) {
    int4 epA[4], epB[4];
    unsigned int xwA[4];
    LOADB(epA, beg)
    LOADX(xwA, epA)
    if (nf >= 2) LOADB(epB, beg + 4)
    for (int b = 0; b + 1 < nf; ++b) {
      unsigned int xwB[4];
      int4 epC[4];
      LOADX(xwB, epB)
      if (b + 2 < nf) LOADB(epC, beg + (b + 2) * 4)
      COMPUTE4(epA, xwA)
#pragma unroll
      for (int j = 0; j < 4; ++j) { epA[j] = epB[j]; xwA[j] = xwB[j]; epB[j] = epC[j]; }
    }
    COMPUTE4(epA, xwA)
  }
  for (int k = beg + (nf << 2); k < end; ++k) {  // <=3 tail edges
    const int4 ep = epack[k];
    const unsigned int xw = *((const unsigned int*)(xl + (size_t)ep.x * HC) + lane);
    EDGE1(ep, xw)
  }

  const float inv = dn > 0.f ? 1.0f / dn : 0.f;
  const float o0 = a0 * inv, o1 = a1 * inv;
  float2 o;
  o.x = o0;
  o.y = o1;
  *((float2*)(outp + (size_t)node * HC) + lane) = o;

  // BN partial stats: block LDS reduce, then 8-way replicated bucket atomics
  ssum[wave * 128 + c0]     = o0;
  ssum[wave * 128 + c0 + 1] = o1;
  ssq[wave * 128 + c0]      = o0 * o0;
  ssq[wave * 128 + c0 + 1]  = o1 * o1;
  __syncthreads();
  if (threadIdx.x < 128) {
    const int c = threadIdx.x;
    const float s1 = ssum[c] + ssum[128 + c] + ssum[256 + c] + ssum[384 + c];
    const float s2 = ssq[c] + ssq[128 + c] + ssq[256 + c] + ssq[384 + c];
    float* bkt = statsB + (blockIdx.x & 7) * 256;
    atomicAdd(&bkt[c], s1);
    atomicAdd(&bkt[128 + c], s2);
  }
}

// ---------------------------------------------------------------------------
// K5: BatchNorm + LeakyReLU(0.01). Each block: reduce the 8 stat buckets
// (threads 0..127, L2-hot), then normalize 1024 consecutive floats (float4).
// ---------------------------------------------------------------------------
__global__ __launch_bounds__(256) void k_bn(const float* __restrict__ statsB,
                                            const float* __restrict__ gamma,
                                            const float* __restrict__ beta,
                                            float* __restrict__ outp) {
  __shared__ float sscale[128], sshift[128];
  const int t = threadIdx.x;
  if (t < 128) {
    float s1 = 0.f, s2 = 0.f;
#pragma unroll
    for (int b = 0; b < 8; ++b) {
      s1 += statsB[b * 256 + t];
      s2 += statsB[b * 256 + 128 + t];
    }
    const float mean = s1 * (1.0f / N_NODES);
    const float var = s2 * (1.0f / N_NODES) - mean * mean;
    const float rstd = rsqrtf(var + 1e-5f);
    const float sc = rstd * gamma[t];
    sscale[t] = sc;
    sshift[t] = beta[t] - mean * sc;
  }
  __syncthreads();
  const size_t base = (size_t)blockIdx.x * 1024 + t * 4;  // 6250*1024 = 6.4M exact
  float4 v = *(const float4*)(outp + base);
  const int c = (t * 4) & 127;
  v.x = fmaf(v.x, sscale[c],     sshift[c]);
  v.y = fmaf(v.y, sscale[c + 1], sshift[c + 1]);
  v.z = fmaf(v.z, sscale[c + 2], sshift[c + 2]);
  v.w = fmaf(v.w, sscale[c + 3], sshift[c + 3]);
  v.x = fmaxf(v.x, 0.01f * v.x);
  v.y = fmaxf(v.y, 0.01f * v.y);
  v.z = fmaxf(v.z, 0.01f * v.z);
  v.w = fmaxf(v.w, 0.01f * v.w);
  *(float4*)(outp + base) = v;
}

// ---------------------------------------------------------------------------
extern "C" void kernel_launch(void* const* d_in, const int* in_sizes, int n_in,
                              void* d_out, int out_size, void* d_ws, size_t ws_size,
                              hipStream_t stream) {
  const float* x     = (const float*)d_in[0];
  const int*   eidx  = (const int*)d_in[1];
  const float* eattr = (const float*)d_in[2];
  const float* Wl    = (const float*)d_in[3];
  const float* bl    = (const float*)d_in[4];
  const float* Wr    = (const float*)d_in[5];
  const float* br    = (const float*)d_in[6];
  const float* We    = (const float*)d_in[7];
  const float* be    = (const float*)d_in[8];
  const float* att   = (const float*)d_in[9];
  // d_in[10] = bias: cancels exactly in BatchNorm mean subtraction -> unused
  const float* gamma = (const float*)d_in[11];
  const float* beta  = (const float*)d_in[12];
  float* out = (float*)d_out;

  char* ws = (char*)d_ws;
  size_t off = 0;
  auto alloc = [&](size_t bytes) {
    size_t o = off;
    off = (off + bytes + 15) & ~size_t(15);
    return o;
  };
  // zero-initialized region first
  const size_t o_deg   = alloc((size_t)(N_NODES + 1) * 4);
  const size_t o_cur   = alloc((size_t)N_NODES * 4);
  const size_t o_cnt   = alloc(16);
  const size_t o_stats = alloc((size_t)8 * 256 * 4);
  const size_t zero_bytes = off;
  // non-zeroed scratch
  const size_t o_offs = alloc((size_t)(N_NODES + 1) * 4);
  const size_t o_ep   = alloc((size_t)N_EDGES * 16);
  const size_t o_wt   = alloc((size_t)256 * 128 * 2);
  const size_t o_xl   = alloc((size_t)N_NODES * HC * 2);
  const size_t o_xr   = alloc((size_t)N_NODES * HC * 2);
  (void)ws_size; (void)in_sizes; (void)n_in; (void)out_size;

  int*   deg    = (int*)(ws + o_deg);
  int*   cur    = (int*)(ws + o_cur);
  int*   cnt    = (int*)(ws + o_cnt);
  float* statsB = (float*)(ws + o_stats);
  int*   offs   = (int*)(ws + o_offs);
  int4*  epack  = (int4*)(ws + o_ep);
  unsigned short* WcatT = (unsigned short*)(ws + o_wt);
  unsigned short* xl    = (unsigned short*)(ws + o_xl);
  unsigned short* xr    = (unsigned short*)(ws + o_xr);

  hipMemsetAsync(ws, 0, zero_bytes, stream);

  k_prep<<<3253, 256, 0, stream>>>(eidx, Wl, Wr, deg, WcatT);
  k_gemm_alloc<<<489, 512, 0, stream>>>(x, WcatT, bl, br, xl, xr, deg, cnt, offs);
  k_scatter<<<3125, 256, 0, stream>>>(eidx, eattr, offs, cur, epack);
  k_attagg<<<12500, 256, 0, stream>>>(offs, deg, epack, xl, xr, We, be, att, out,
                                      statsB);
  k_bn<<<6250, 256, 0, stream>>>(statsB, gamma, beta, out);
}